// Round 2
// baseline (133.486 us; speedup 1.0000x reference)
//
#include <hip/hip_runtime.h>

// Problem constants (fixed by reference)
#define GS    256
#define PARAM 128
#define KC    32
#define I1    64
#define I2    32
#define PK    96        // PARAM - KC
#define B_    4
#define NROWS (B_ * GS) // 1024
#define EPS   1e-3f
#define KDIV_INV (1.0f / 16.0f)
#define CHUNK 32

// Workspace layout (float offsets)
constexpr int U_OFF   = 0;                   // NROWS*I1 = 65536
constexpr int W_OFF   = NROWS * I1;          // 65536
constexpr int M2F_OFF = 2 * NROWS * I1;      // 131072 (I1*I2 = 2048)
constexpr int C2_OFF  = M2F_OFF + I1 * I2;   // 133120 (I2)
constexpr int M3F_OFF = C2_OFF + I2;         // 133152 (I2*PK = 3072)
constexpr int C3_OFF  = M3F_OFF + I2 * PK;   // 136224 (PK)
constexpr int C1_OFF  = C3_OFF + PK;         // 136320 (I1)
// total floats = 136384 -> 545,536 bytes of d_ws

// Kernel A: per-row u/w projections with BN1 folded; block NROWS folds BN2/BN3.
__global__ __launch_bounds__(128) void glmlp_precompute(
    const float* __restrict__ val, const float* __restrict__ M1,
    const float* __restrict__ B1,
    const float* __restrict__ M2, const float* __restrict__ B2,
    const float* __restrict__ M3, const float* __restrict__ B3,
    const float* __restrict__ g1, const float* __restrict__ b1,
    const float* __restrict__ m1, const float* __restrict__ v1,
    const float* __restrict__ g2, const float* __restrict__ b2,
    const float* __restrict__ m2, const float* __restrict__ v2,
    const float* __restrict__ g3, const float* __restrict__ b3,
    const float* __restrict__ m3, const float* __restrict__ v3,
    float* __restrict__ ws, float* __restrict__ out)
{
    const int blk = blockIdx.x;
    const int t = threadIdx.x;

    if (blk < NROWS) {
        __shared__ float vrow[PARAM];
        const int r = blk;
        if (t < PARAM) vrow[t] = val[r * PARAM + t];
        __syncthreads();

        // exact copy: con = val[:, :, :KC]
        if (t < KC) out[r * PARAM + t] = vrow[t];

        if (t < 2 * I1) {
            const int i = t & (I1 - 1);
            const bool isU = (t < I1);
            float acc = 0.f;
            if (isU) {
                // u_raw[i] = sum_p val[p] * (M1_top[p][i] - M1_bot[p][i])
                #pragma unroll 8
                for (int p = 0; p < PARAM; ++p)
                    acc += vrow[p] * (M1[p * I1 + i] - M1[(PARAM + p) * I1 + i]);
            } else {
                // w_raw[i] = sum_p val[p] * M1_bot[p][i]
                #pragma unroll 8
                for (int p = 0; p < PARAM; ++p)
                    acc += vrow[p] * M1[(PARAM + p) * I1 + i];
            }
            const float s1 = g1[i] * rsqrtf(v1[i] + EPS);
            ws[(isU ? U_OFF : W_OFF) + r * I1 + i] = acc * s1;
        }
    } else {
        // BN folding block
        if (t < I1) {
            const float s1 = g1[t] * rsqrtf(v1[t] + EPS);
            ws[C1_OFF + t] = B1[t] * s1 + b1[t] - m1[t] * s1;
        }
        if (t < I2) {
            const float s2 = g2[t] * rsqrtf(v2[t] + EPS);
            ws[C2_OFF + t] = B2[t] * s2 + b2[t] - m2[t] * s2;
        }
        if (t < PK) {
            const float s3 = g3[t] * rsqrtf(v3[t] + EPS);
            ws[C3_OFF + t] = B3[t] * s3 + b3[t] - m3[t] * s3;
        }
        for (int idx = t; idx < I1 * I2; idx += 128) {
            const int j = idx & (I2 - 1);
            const float s2 = g2[j] * rsqrtf(v2[j] + EPS);
            ws[M2F_OFF + idx] = M2[idx] * s2;
        }
        for (int idx = t; idx < I2 * PK; idx += 128) {
            const int k = idx % PK;
            const float s3 = g3[k] * rsqrtf(v3[k] + EPS);
            ws[M3F_OFF + idx] = M3[idx] * s3;
        }
    }
}

// Kernel B: one block per (b,x) row. Compact active y's, run the tiny MLP
// only on active pairs, accumulate, clip, store.
__global__ __launch_bounds__(256) void glmlp_pairs(
    const float* __restrict__ mat, const float* __restrict__ ws,
    float* __restrict__ out)
{
    __shared__ float m2s[I1 * I2];     // 8 KB
    __shared__ float m3s[I2 * PK];     // 12 KB
    __shared__ float uxs[I1];          // u_x + c1
    __shared__ float c2s[I2];
    __shared__ float c3s[PK];
    __shared__ float H1[CHUNK][I1];    // 8 KB
    __shared__ float H2[CHUNK][I2];    // 4 KB
    __shared__ int   acty[GS];
    __shared__ float actv[GS];
    __shared__ int   cnt;

    const int r = blockIdx.x;
    const int t = threadIdx.x;
    // w vectors are stored per GLOBAL row r' = b*GS + y. Batch base for this block:
    const int wbase = (r & ~(GS - 1));   // b * GS
    const float* __restrict__ W = ws + W_OFF;

    if (t == 0) cnt = 0;
    for (int idx = t; idx < I1 * I2; idx += 256) m2s[idx] = ws[M2F_OFF + idx];
    for (int idx = t; idx < I2 * PK; idx += 256) m3s[idx] = ws[M3F_OFF + idx];
    if (t < I2) c2s[t] = ws[C2_OFF + t];
    if (t < PK) c3s[t] = ws[C3_OFF + t];
    if (t < I1) uxs[t] = ws[U_OFF + r * I1 + t] + ws[C1_OFF + t];
    __syncthreads();

    // compact the mask row (mat values are 0/1 but we keep the value anyway)
    const float mv = mat[r * GS + t];
    if (mv != 0.0f) {
        const int idx = atomicAdd(&cnt, 1);
        acty[idx] = t;
        actv[idx] = mv;
    }
    __syncthreads();
    const int n = cnt;

    // per-thread M3 column (k = t) held in registers
    float m3col[I2];
    if (t < PK) {
        #pragma unroll
        for (int i = 0; i < I2; ++i) m3col[i] = m3s[i * PK + t];
    }

    float acc = 0.0f;

    for (int base = 0; base < n; base += CHUNK) {
        const int nc = min(CHUNK, n - base);

        // Layer 1: H1[p][i] = relu(u'_x[i] + w'_y[i] + c1[i])  (c1 folded into uxs)
        for (int idx = t; idx < nc * I1; idx += 256) {
            const int p = idx >> 6, i = idx & (I1 - 1);
            const int y = acty[base + p];
            H1[p][i] = fmaxf(uxs[i] + W[(wbase + y) * I1 + i], 0.0f);
        }
        __syncthreads();

        // Layer 2: H2[p][j] = relu(H1[p] . M2f[:,j] + c2[j])
        for (int idx = t; idx < nc * I2; idx += 256) {
            const int p = idx >> 5, j = idx & (I2 - 1);
            float a = c2s[j];
            const float4* h1p4 = (const float4*)(&H1[p][0]);
            #pragma unroll
            for (int i4 = 0; i4 < I1 / 4; ++i4) {
                const float4 h = h1p4[i4];
                const int i = i4 * 4;
                a = fmaf(h.x, m2s[(i + 0) * I2 + j], a);
                a = fmaf(h.y, m2s[(i + 1) * I2 + j], a);
                a = fmaf(h.z, m2s[(i + 2) * I2 + j], a);
                a = fmaf(h.w, m2s[(i + 3) * I2 + j], a);
            }
            H2[p][j] = fmaxf(a, 0.0f);
        }
        __syncthreads();

        // Layer 3 + masked accumulation: acc_k += relu(H2[p] . M3f[:,k] + c3[k]) * mat
        if (t < PK) {
            for (int p = 0; p < nc; ++p) {
                float a = c3s[t];
                const float4* h2p4 = (const float4*)(&H2[p][0]);
                #pragma unroll
                for (int i4 = 0; i4 < I2 / 4; ++i4) {
                    const float4 h = h2p4[i4];
                    const int i = i4 * 4;
                    a = fmaf(h.x, m3col[i + 0], a);
                    a = fmaf(h.y, m3col[i + 1], a);
                    a = fmaf(h.z, m3col[i + 2], a);
                    a = fmaf(h.w, m3col[i + 3], a);
                }
                acc += fmaxf(a, 0.0f) * actv[base + p];
            }
        }
        __syncthreads();
    }

    if (t < PK) {
        float v = acc * KDIV_INV;
        v = fminf(fmaxf(v, -1.0f), 1.0f);
        out[r * PARAM + KC + t] = v;
    }
}

extern "C" void kernel_launch(void* const* d_in, const int* in_sizes, int n_in,
                              void* d_out, int out_size, void* d_ws, size_t ws_size,
                              hipStream_t stream) {
    const float* mat = (const float*)d_in[0];
    const float* val = (const float*)d_in[1];
    const float* M1  = (const float*)d_in[2];
    const float* B1  = (const float*)d_in[3];
    const float* M2  = (const float*)d_in[4];
    const float* B2  = (const float*)d_in[5];
    const float* M3  = (const float*)d_in[6];
    const float* B3  = (const float*)d_in[7];
    const float* g1  = (const float*)d_in[8];
    const float* b1  = (const float*)d_in[9];
    const float* m1  = (const float*)d_in[10];
    const float* v1  = (const float*)d_in[11];
    const float* g2  = (const float*)d_in[12];
    const float* b2  = (const float*)d_in[13];
    const float* m2  = (const float*)d_in[14];
    const float* v2  = (const float*)d_in[15];
    const float* g3  = (const float*)d_in[16];
    const float* b3  = (const float*)d_in[17];
    const float* m3  = (const float*)d_in[18];
    const float* v3  = (const float*)d_in[19];

    float* ws  = (float*)d_ws;
    float* out = (float*)d_out;

    hipLaunchKernelGGL(glmlp_precompute, dim3(NROWS + 1), dim3(128), 0, stream,
                       val, M1, B1, M2, B2, M3, B3,
                       g1, b1, m1, v1, g2, b2, m2, v2, g3, b3, m3, v3,
                       ws, out);

    hipLaunchKernelGGL(glmlp_pairs, dim3(NROWS), dim3(256), 0, stream,
                       mat, ws, out);
}

// Round 3
// 124.416 us; speedup vs baseline: 1.0729x; 1.0729x over previous
//
#include <hip/hip_runtime.h>

// Problem constants (fixed by reference)
#define GS    256
#define PARAM 128
#define KC    32
#define I1    64
#define I2    32
#define PK    96        // PARAM - KC
#define B_    4
#define NROWS (B_ * GS) // 1024
#define EPS   1e-3f
#define KDIV_INV (1.0f / 16.0f)
#define CHUNK 32

// Workspace layout (float offsets)
constexpr int U_OFF   = 0;                   // NROWS*I1 = 65536
constexpr int W_OFF   = NROWS * I1;          // 65536
constexpr int M2F_OFF = 2 * NROWS * I1;      // 131072 (I1*I2 = 2048)
constexpr int C2_OFF  = M2F_OFF + I1 * I2;   // (I2)
constexpr int M3F_OFF = C2_OFF + I2;         // (I2*PK = 3072)
constexpr int C3_OFF  = M3F_OFF + I2 * PK;   // (PK)
constexpr int C1_OFF  = C3_OFF + PK;         // (I1)

// Kernel A: one block per row. 256 thr = 64 i-lanes x 4 quarter-dots.
// u = val.(M1top - M1bot) = T - W, so compute T and W (1 load per MAC each).
__global__ __launch_bounds__(256) void glmlp_precompute(
    const float* __restrict__ val, const float* __restrict__ M1,
    const float* __restrict__ B1,
    const float* __restrict__ M2, const float* __restrict__ B2,
    const float* __restrict__ M3, const float* __restrict__ B3,
    const float* __restrict__ g1, const float* __restrict__ b1,
    const float* __restrict__ m1, const float* __restrict__ v1,
    const float* __restrict__ g2, const float* __restrict__ b2,
    const float* __restrict__ m2, const float* __restrict__ v2,
    const float* __restrict__ g3, const float* __restrict__ b3,
    const float* __restrict__ m3, const float* __restrict__ v3,
    float* __restrict__ ws, float* __restrict__ out)
{
    const int blk = blockIdx.x;
    const int t = threadIdx.x;

    if (blk < NROWS) {
        __shared__ float vrow[PARAM];
        __shared__ float red[4][I1];
        const int r = blk;
        if (t < PARAM) vrow[t] = val[r * PARAM + t];
        __syncthreads();

        // exact copy: con = val[:, :, :KC]
        if (t < KC) out[r * PARAM + t] = vrow[t];

        const int i = t & (I1 - 1);
        const int q = t >> 6;                         // 0..3
        // q=0,1 -> T (M1 top half); q=2,3 -> W (M1 bottom half)
        const float* __restrict__ Mb = M1 + ((q >> 1) ? (PARAM * I1) : 0);
        const int p0 = (q & 1) * 64;
        float acc = 0.f;
        #pragma unroll 8
        for (int p = 0; p < 64; ++p)
            acc = fmaf(vrow[p0 + p], Mb[(p0 + p) * I1 + i], acc);
        red[q][i] = acc;
        __syncthreads();

        if (q == 0) {
            const float T  = red[0][i] + red[1][i];
            const float Wv = red[2][i] + red[3][i];
            const float s1 = g1[i] * rsqrtf(v1[i] + EPS);
            ws[U_OFF + r * I1 + i] = (T - Wv) * s1;
            ws[W_OFF + r * I1 + i] = Wv * s1;
        }
    } else {
        // BN folding block
        if (t < I1) {
            const float s1 = g1[t] * rsqrtf(v1[t] + EPS);
            ws[C1_OFF + t] = B1[t] * s1 + b1[t] - m1[t] * s1;
        }
        if (t < I2) {
            const float s2 = g2[t] * rsqrtf(v2[t] + EPS);
            ws[C2_OFF + t] = B2[t] * s2 + b2[t] - m2[t] * s2;
        }
        if (t < PK) {
            const float s3 = g3[t] * rsqrtf(v3[t] + EPS);
            ws[C3_OFF + t] = B3[t] * s3 + b3[t] - m3[t] * s3;
        }
        for (int idx = t; idx < I1 * I2; idx += 256) {
            const int j = idx & (I2 - 1);
            const float s2 = g2[j] * rsqrtf(v2[j] + EPS);
            ws[M2F_OFF + idx] = M2[idx] * s2;
        }
        for (int idx = t; idx < I2 * PK; idx += 256) {
            const int k = idx % PK;
            const float s3 = g3[k] * rsqrtf(v3[k] + EPS);
            ws[M3F_OFF + idx] = M3[idx] * s3;
        }
    }
}

// Kernel B: one block per (b,x) row. Compact active y's, tiny MLP on active
// pairs only. Layer 3 parallelized over 2 pair-halves x 96 k with dual
// interleaved FMA chains (critical path /4 vs serial version).
__global__ __launch_bounds__(256) void glmlp_pairs(
    const float* __restrict__ mat, const float* __restrict__ ws,
    float* __restrict__ out)
{
    __shared__ float m2s[I1 * I2];      // 8 KB
    __shared__ float uxs[I1];           // u_x + c1
    __shared__ float c2s[I2];
    __shared__ float c3s[PK];
    __shared__ float H1[CHUNK][I1];     // 8 KB
    __shared__ float H2[CHUNK][I2];     // 4 KB
    __shared__ int   acty[GS];          // 1 KB
    __shared__ float partial[2][PK];
    __shared__ int   cnt;

    const int r = blockIdx.x;
    const int t = threadIdx.x;
    const int wbase = (r & ~(GS - 1));   // b * GS (w vectors indexed by global row)
    const float* __restrict__ W = ws + W_OFF;

    if (t == 0) cnt = 0;
    for (int idx = t; idx < I1 * I2; idx += 256) m2s[idx] = ws[M2F_OFF + idx];
    if (t < I2) c2s[t] = ws[C2_OFF + t];
    if (t < PK) c3s[t] = ws[C3_OFF + t];
    if (t < I1) uxs[t] = ws[U_OFF + r * I1 + t] + ws[C1_OFF + t];
    const float mv = mat[r * GS + t];

    // per-thread M3 column from global (L2-hot, coalesced over k)
    const bool l3 = (t < 2 * PK);
    const int k = l3 ? (t % PK) : 0;
    const int h = l3 ? (t / PK) : 0;
    float m3col[I2];
    if (l3) {
        #pragma unroll
        for (int ii = 0; ii < I2; ++ii) m3col[ii] = ws[M3F_OFF + ii * PK + k];
    }
    __syncthreads();

    // compact the mask row (values are exactly 0.0/1.0)
    if (mv != 0.0f) acty[atomicAdd(&cnt, 1)] = t;
    __syncthreads();
    const int n = cnt;

    float acc = 0.0f;

    for (int base = 0; base < n; base += CHUNK) {
        const int nc = min(CHUNK, n - base);

        // Layer 1: H1[p][i] = relu(u'_x[i] + w'_y[i])   (c1 folded into uxs)
        for (int idx = t; idx < nc * I1; idx += 256) {
            const int p = idx >> 6, i = idx & (I1 - 1);
            const int y = acty[base + p];
            H1[p][i] = fmaxf(uxs[i] + W[(wbase + y) * I1 + i], 0.0f);
        }
        __syncthreads();

        // Layer 2: H2[p][j] = relu(H1[p] . M2f[:,j] + c2[j])
        for (int idx = t; idx < nc * I2; idx += 256) {
            const int p = idx >> 5, j = idx & (I2 - 1);
            float a = c2s[j];
            const float4* h1p4 = (const float4*)(&H1[p][0]);
            #pragma unroll
            for (int i4 = 0; i4 < I1 / 4; ++i4) {
                const float4 hv = h1p4[i4];
                const int i = i4 * 4;
                a = fmaf(hv.x, m2s[(i + 0) * I2 + j], a);
                a = fmaf(hv.y, m2s[(i + 1) * I2 + j], a);
                a = fmaf(hv.z, m2s[(i + 2) * I2 + j], a);
                a = fmaf(hv.w, m2s[(i + 3) * I2 + j], a);
            }
            H2[p][j] = fmaxf(a, 0.0f);
        }
        __syncthreads();

        // Layer 3: half h handles pairs p = h, h+2, ...; dual chains.
        if (l3) {
            int p = h;
            for (; p + 2 < nc; p += 4) {
                float a0 = c3s[k], a1 = c3s[k];
                const float4* A4 = (const float4*)(&H2[p][0]);
                const float4* B4 = (const float4*)(&H2[p + 2][0]);
                #pragma unroll
                for (int i4 = 0; i4 < I2 / 4; ++i4) {
                    const float4 ha = A4[i4];
                    const float4 hb = B4[i4];
                    const int i = i4 * 4;
                    a0 = fmaf(ha.x, m3col[i + 0], a0);
                    a1 = fmaf(hb.x, m3col[i + 0], a1);
                    a0 = fmaf(ha.y, m3col[i + 1], a0);
                    a1 = fmaf(hb.y, m3col[i + 1], a1);
                    a0 = fmaf(ha.z, m3col[i + 2], a0);
                    a1 = fmaf(hb.z, m3col[i + 2], a1);
                    a0 = fmaf(ha.w, m3col[i + 3], a0);
                    a1 = fmaf(hb.w, m3col[i + 3], a1);
                }
                acc += fmaxf(a0, 0.0f) + fmaxf(a1, 0.0f);
            }
            for (; p < nc; p += 2) {
                float a0 = c3s[k];
                const float4* A4 = (const float4*)(&H2[p][0]);
                #pragma unroll
                for (int i4 = 0; i4 < I2 / 4; ++i4) {
                    const float4 ha = A4[i4];
                    const int i = i4 * 4;
                    a0 = fmaf(ha.x, m3col[i + 0], a0);
                    a0 = fmaf(ha.y, m3col[i + 1], a0);
                    a0 = fmaf(ha.z, m3col[i + 2], a0);
                    a0 = fmaf(ha.w, m3col[i + 3], a0);
                }
                acc += fmaxf(a0, 0.0f);
            }
        }
        // no trailing barrier needed: next iter's post-L1 barrier fences H2 reuse
    }

    if (l3) partial[h][k] = acc;
    __syncthreads();

    if (t < PK) {
        float v = (partial[0][t] + partial[1][t]) * KDIV_INV;
        v = fminf(fmaxf(v, -1.0f), 1.0f);
        out[r * PARAM + KC + t] = v;
    }
}

extern "C" void kernel_launch(void* const* d_in, const int* in_sizes, int n_in,
                              void* d_out, int out_size, void* d_ws, size_t ws_size,
                              hipStream_t stream) {
    const float* mat = (const float*)d_in[0];
    const float* val = (const float*)d_in[1];
    const float* M1  = (const float*)d_in[2];
    const float* B1  = (const float*)d_in[3];
    const float* M2  = (const float*)d_in[4];
    const float* B2  = (const float*)d_in[5];
    const float* M3  = (const float*)d_in[6];
    const float* B3  = (const float*)d_in[7];
    const float* g1  = (const float*)d_in[8];
    const float* b1  = (const float*)d_in[9];
    const float* m1  = (const float*)d_in[10];
    const float* v1  = (const float*)d_in[11];
    const float* g2  = (const float*)d_in[12];
    const float* b2  = (const float*)d_in[13];
    const float* m2  = (const float*)d_in[14];
    const float* v2  = (const float*)d_in[15];
    const float* g3  = (const float*)d_in[16];
    const float* b3  = (const float*)d_in[17];
    const float* m3  = (const float*)d_in[18];
    const float* v3  = (const float*)d_in[19];

    float* ws  = (float*)d_ws;
    float* out = (float*)d_out;

    hipLaunchKernelGGL(glmlp_precompute, dim3(NROWS + 1), dim3(256), 0, stream,
                       val, M1, B1, M2, B2, M3, B3,
                       g1, b1, m1, v1, g2, b2, m2, v2, g3, b3, m3, v3,
                       ws, out);

    hipLaunchKernelGGL(glmlp_pairs, dim3(NROWS), dim3(256), 0, stream,
                       mat, ws, out);
}